// Round 16
// baseline (749.908 us; speedup 1.0000x reference)
//
#include <hip/hip_runtime.h>
#include <math.h>

#define Bsz 16
#define Tt 24
#define Nn 256
#define Fp 6
#define Hh 64
#define PredL 12
#define Fw 4
#define M1 32
#define TCHUNK 12
#define DEG2RAD 0.017453292519943295f
#define IDX2(t, b) ((t) * Bsz + (b))

// ---------------------------------------------------------------------------
// P0+PT: blocks 0..255 build packed pk[i][j] = {Ac,As}; block 256 repacks
// weights (wgc2T[k][g], wm1T, wm2T, wihP/whhP float4 {r,z,n,0} per [k][lane]).
// ---------------------------------------------------------------------------
__global__ __launch_bounds__(256) void k_prep(
    const float* __restrict__ coords, const float* __restrict__ adj,
    const float* __restrict__ wgc2, const float* __restrict__ wih,
    const float* __restrict__ whh,  const float* __restrict__ wm1,
    const float* __restrict__ wm2,
    float2* __restrict__ pk,
    float* __restrict__ wgc2T, float* __restrict__ wm1T, float* __restrict__ wm2T,
    float4* __restrict__ wihP, float4* __restrict__ whhP) {
  int tid = threadIdx.x;
  if (blockIdx.x < Nn) {
    int i = blockIdx.x;
    int j = tid;
    float dx = coords[2 * j]     - coords[2 * i];
    float dy = coords[2 * j + 1] - coords[2 * i + 1];
    float ang = atan2f(dy, dx);
    float a = adj[i * Nn + j];
    pk[i * Nn + j] = make_float2(a * cosf(ang), a * sinf(ang));
    return;
  }
  for (int idx = tid; idx < Hh * Hh; idx += 256) {
    int g = idx / Hh, k = idx % Hh;
    wgc2T[k * Hh + g] = wgc2[g * Hh + k];
  }
  for (int idx = tid; idx < M1 * Hh; idx += 256) {
    int m = idx / Hh, k = idx % Hh;
    wm1T[k * M1 + m] = wm1[m * Hh + k];
  }
  for (int idx = tid; idx < Fp * M1; idx += 256) {
    int f = idx / M1, m = idx % M1;
    wm2T[m * Fp + f] = wm2[f * M1 + m];
  }
  for (int idx = tid; idx < Hh * 64; idx += 256) {
    int k = idx >> 6, lane = idx & 63;
    wihP[idx] = make_float4(wih[(0 * 64 + lane) * Hh + k],
                            wih[(1 * 64 + lane) * Hh + k],
                            wih[(2 * 64 + lane) * Hh + k], 0.f);
    whhP[idx] = make_float4(whh[(0 * 64 + lane) * Hh + k],
                            whh[(1 * 64 + lane) * Hh + k],
                            whh[(2 * 64 + lane) * Hh + k], 0.f);
  }
}

// ---------------------------------------------------------------------------
// E: fused encoder, half-split: 2 blocks per (t,b); each runs deg + gconv1
// for ALL rows (h1 must be complete) but pass-2/W2/store for its 128 rows.
// 512 blocks = exactly 2/CU -> balanced LDS-pipe makespan.
// ---------------------------------------------------------------------------
__global__ __launch_bounds__(256) void k_enc(
    const float2* __restrict__ pk, const float* __restrict__ hp,
    const float* __restrict__ hw,
    const float* __restrict__ wgc1, const float* __restrict__ bgc1,
    const float* __restrict__ wgc2T, const float* __restrict__ bgc2,
    float* __restrict__ sf_all,
    float* __restrict__ d23, float* __restrict__ e23) {
  __shared__ float d_lds[Nn];
  __shared__ float e_lds[Nn];
  __shared__ __align__(16) float u_s[Nn * 8];     // 8KB
  __shared__ __align__(16) float h1_s[Nn * 68];   // 69.6KB
  int half = blockIdx.x & 1;
  int tb = blockIdx.x >> 1, t = tb / Bsz, b = tb % Bsz;
  int tid = threadIdx.x;
  int i = tid;
  float spd = hw[(b * Tt + t) * Fw + 2];
  float rad = hw[(b * Tt + t) * Fw + 1] * DEG2RAD;
  float scr = spd * cosf(rad), ssr = spd * sinf(rad);

  // ---- pass 0: degrees (from column i of pk), all rows ----
  {
    float rs = 0.f, cs = 0.f;
#pragma unroll 4
    for (int j = 0; j < Nn; ++j) {
      float2 pv = pk[j * Nn + i];
      float v = pv.x * scr + pv.y * ssr;   // V(j,i)
      cs += fmaxf(v, 0.f);
      rs += fmaxf(-v, 0.f);
    }
    float2 pd = pk[i * Nn + i];
    float vii = pd.x * scr + pd.y * ssr;
    rs += vii;  // diag fix
    float di = 1.f / (sqrtf(rs + 1.f) + 1e-6f);
    float ei = 1.f / (sqrtf(cs + 1.f) + 1e-6f);
    d_lds[i] = di; e_lds[i] = ei;
    if (t == Tt - 1 && half == 0) { d23[b * Nn + i] = di; e23[b * Nn + i] = ei; }
  }
  __syncthreads();

  // ---- stage u = d_j * x ----
  {
    const float* xsrc = hp + (long)(b * Tt + t) * Nn * Fp;
    for (int idx = tid; idx < Nn * Fp; idx += 256) {
      int j = idx / Fp, f = idx - j * Fp;
      u_s[j * 8 + f] = d_lds[j] * xsrc[idx];
    }
    u_s[tid * 8 + 6] = 0.f;
    u_s[tid * 8 + 7] = 0.f;
  }
  __syncthreads();

  // ---- pass 1: gconv1 for row i (ALL rows); e-scaled h1 row -> LDS ----
  {
    float a0 = 0.f, a1 = 0.f, a2 = 0.f, a3 = 0.f, a4 = 0.f, a5 = 0.f;
#pragma unroll 2
    for (int j = 0; j < Nn; ++j) {
      float2 pv = pk[j * Nn + i];
      float v = pv.x * scr + pv.y * ssr;
      float w = fmaxf(-v, 0.f);            // wout[i][j], wrong on diag
      float4 ul = *(const float4*)&u_s[j * 8];
      float4 uh = *(const float4*)&u_s[j * 8 + 4];
      a0 += w * ul.x; a1 += w * ul.y; a2 += w * ul.z;
      a3 += w * ul.w; a4 += w * uh.x; a5 += w * uh.y;
    }
    float2 pd = pk[i * Nn + i];
    float vii = pd.x * scr + pd.y * ssr;
    float di = d_lds[i], ei = e_lds[i];
    float c1 = vii + 1.f;  // diag fix + identity
    float y0 = di * (a0 + c1 * u_s[i * 8 + 0]);
    float y1 = di * (a1 + c1 * u_s[i * 8 + 1]);
    float y2 = di * (a2 + c1 * u_s[i * 8 + 2]);
    float y3 = di * (a3 + c1 * u_s[i * 8 + 3]);
    float y4 = di * (a4 + c1 * u_s[i * 8 + 4]);
    float y5 = di * (a5 + c1 * u_s[i * 8 + 5]);
#pragma unroll
    for (int g4 = 0; g4 < 16; ++g4) {
      float4 hv;
#pragma unroll
      for (int q = 0; q < 4; ++q) {
        int g = g4 * 4 + q;
        float v2 = bgc1[g] + wgc1[g * Fp + 0] * y0 + wgc1[g * Fp + 1] * y1 +
                   wgc1[g * Fp + 2] * y2 + wgc1[g * Fp + 3] * y3 +
                   wgc1[g * Fp + 4] * y4 + wgc1[g * Fp + 5] * y5;
        ((float*)&hv)[q] = fmaxf(v2, 0.f) * ei;
      }
      *(float4*)&h1_s[i * 68 + g4 * 4] = hv;
    }
  }
  __syncthreads();

  // ---- pass 2 + W2 (own 128 rows only; threads 0..127 active) ----
  if (tid < 128) {
    int i2 = half * 128 + tid;
    float z[64];
#pragma unroll
    for (int k = 0; k < 64; ++k) z[k] = 0.f;
#pragma unroll 2
    for (int j = 0; j < Nn; ++j) {
      float2 pv = pk[j * Nn + i2];
      float v = pv.x * scr + pv.y * ssr;     // V(j,i2)
      float wf = fmaxf(v, 0.f) + ((j == i2) ? 1.f : 0.f);
#pragma unroll
      for (int g4 = 0; g4 < 16; ++g4) {
        float4 h4 = *(const float4*)&h1_s[j * 68 + g4 * 4];
        z[g4 * 4 + 0] += wf * h4.x;
        z[g4 * 4 + 1] += wf * h4.y;
        z[g4 * 4 + 2] += wf * h4.z;
        z[g4 * 4 + 3] += wf * h4.w;
      }
    }
    {
      float ei = e_lds[i2];
#pragma unroll
      for (int k = 0; k < 64; ++k) z[k] *= ei;
    }
    __syncthreads();   // all pass-2 h1_s reads done; reuse own rows for sf

    // ---- W2 + relu -> staged in h1_s (own rows) ----
#pragma unroll
    for (int c = 0; c < 4; ++c) {
      float s[16];
#pragma unroll
      for (int q = 0; q < 16; ++q) s[q] = bgc2[c * 16 + q];
#pragma unroll
      for (int k = 0; k < 64; ++k) {
        float zk = z[k];
#pragma unroll
        for (int q = 0; q < 16; ++q) s[q] += wgc2T[k * Hh + c * 16 + q] * zk;
      }
#pragma unroll
      for (int q4 = 0; q4 < 4; ++q4) {
        float4 sv = make_float4(fmaxf(s[q4 * 4 + 0], 0.f), fmaxf(s[q4 * 4 + 1], 0.f),
                                fmaxf(s[q4 * 4 + 2], 0.f), fmaxf(s[q4 * 4 + 3], 0.f));
        *(float4*)&h1_s[i2 * 68 + c * 16 + q4 * 4] = sv;
      }
    }
  } else {
    __syncthreads();   // matching barrier for inactive half
  }
  __syncthreads();
  // ---- coalesced store of own 128 rows ----
  long base = (long)IDX2(t, b) * Nn * Hh;
  for (int idx = tid; idx < 128 * 16; idx += 256) {
    int j = half * 128 + (idx >> 4), g4 = idx & 15;
    *(float4*)&sf_all[base + j * Hh + g4 * 4] = *(const float4*)&h1_s[j * 68 + g4 * 4];
  }
}

// ---------------------------------------------------------------------------
// GI: gi = sf @ W_ih^T + b_ih for TCHUNK timesteps (16 rows/wave, VALU-bound)
// ---------------------------------------------------------------------------
__global__ __launch_bounds__(256) void k_gi(
    const float* __restrict__ sf_all, const float4* __restrict__ wihP,
    const float* __restrict__ bih, float* __restrict__ gi, int t0) {
  __shared__ float sf_c[4][16][64];
  int tid = threadIdx.x, w = tid >> 6, lane = tid & 63;
  int rowc0 = blockIdx.x * 64 + w * 16;
  long rowg0 = (long)t0 * (Bsz * Nn) + rowc0;
#pragma unroll
  for (int rr = 0; rr < 16; ++rr)
    sf_c[w][rr][lane] = sf_all[(rowg0 + rr) * Hh + lane];
  float bi_r = bih[lane], bi_z = bih[64 + lane], bi_n = bih[128 + lane];
  float ar[16], az[16], an[16];
#pragma unroll
  for (int rr = 0; rr < 16; ++rr) { ar[rr] = bi_r; az[rr] = bi_z; an[rr] = bi_n; }
#pragma unroll 2
  for (int kb = 0; kb < 16; ++kb) {
    int k0 = kb * 4;
    float4 wi0 = wihP[(k0 + 0) * 64 + lane];
    float4 wi1 = wihP[(k0 + 1) * 64 + lane];
    float4 wi2 = wihP[(k0 + 2) * 64 + lane];
    float4 wi3 = wihP[(k0 + 3) * 64 + lane];
#pragma unroll
    for (int rr = 0; rr < 16; ++rr) {
      const float4 s4 = *(const float4*)&sf_c[w][rr][k0];
      ar[rr] += s4.x * wi0.x + s4.y * wi1.x + s4.z * wi2.x + s4.w * wi3.x;
      az[rr] += s4.x * wi0.y + s4.y * wi1.y + s4.z * wi2.y + s4.w * wi3.y;
      an[rr] += s4.x * wi0.z + s4.y * wi1.z + s4.z * wi2.z + s4.w * wi3.z;
    }
  }
#pragma unroll
  for (int rr = 0; rr < 16; ++rr) {
    long rowc = rowc0 + rr;
    gi[(rowc * 3 + 0) * 64 + lane] = ar[rr];
    gi[(rowc * 3 + 1) * 64 + lane] = az[rr];
    gi[(rowc * 3 + 2) * 64 + lane] = an[rr];
  }
}

// ---------------------------------------------------------------------------
// GRU scan over one chunk (gh only; whh streamed; h broadcast via LDS rows)
// ---------------------------------------------------------------------------
__global__ __launch_bounds__(256) void k_gru_scan4(
    const float* __restrict__ gi, const float4* __restrict__ whhP,
    const float* __restrict__ bhh, float* __restrict__ hstate,
    int t0, int nt) {
  __shared__ float h_s[16][64];
  int b = blockIdx.x >> 4;
  int i0 = (blockIdx.x & 15) * 16;
  int tid = threadIdx.x, w = tid >> 6, lane = tid & 63;
  float bh_r = bhh[lane], bh_z = bhh[64 + lane], bh_n = bhh[128 + lane];
  float h_reg[4];
#pragma unroll
  for (int rr = 0; rr < 4; ++rr) {
    float hv = (t0 == 0) ? 0.f
                         : hstate[((long)b * Nn + i0 + w * 4 + rr) * Hh + lane];
    h_reg[rr] = hv;
    h_s[w * 4 + rr][lane] = hv;
  }
  for (int tl = 0; tl < nt; ++tl) {
    long rbase = ((long)tl * Bsz + b) * Nn + i0 + w * 4;
    float gr[4], gz[4], gn[4], hr[4], hz[4], hn[4];
#pragma unroll
    for (int rr = 0; rr < 4; ++rr) {
      gr[rr] = gi[((rbase + rr) * 3 + 0) * 64 + lane];
      gz[rr] = gi[((rbase + rr) * 3 + 1) * 64 + lane];
      gn[rr] = gi[((rbase + rr) * 3 + 2) * 64 + lane];
      hr[rr] = bh_r; hz[rr] = bh_z; hn[rr] = bh_n;
    }
#pragma unroll 4
    for (int kb = 0; kb < 16; ++kb) {
      int k0 = kb * 4;
      float4 wh0 = whhP[(k0 + 0) * 64 + lane];
      float4 wh1 = whhP[(k0 + 1) * 64 + lane];
      float4 wh2 = whhP[(k0 + 2) * 64 + lane];
      float4 wh3 = whhP[(k0 + 3) * 64 + lane];
#pragma unroll
      for (int rr = 0; rr < 4; ++rr) {
        const float4 h4 = *(const float4*)&h_s[w * 4 + rr][k0];
        hr[rr] += h4.x * wh0.x + h4.y * wh1.x + h4.z * wh2.x + h4.w * wh3.x;
        hz[rr] += h4.x * wh0.y + h4.y * wh1.y + h4.z * wh2.y + h4.w * wh3.y;
        hn[rr] += h4.x * wh0.z + h4.y * wh1.z + h4.z * wh2.z + h4.w * wh3.z;
      }
    }
#pragma unroll
    for (int rr = 0; rr < 4; ++rr) {
      float rg = 1.f / (1.f + expf(-(gr[rr] + hr[rr])));
      float zg = 1.f / (1.f + expf(-(gz[rr] + hz[rr])));
      float ng = tanhf(gn[rr] + rg * hn[rr]);
      float hv = (1.f - zg) * ng + zg * h_reg[rr];
      h_reg[rr] = hv;
      h_s[w * 4 + rr][lane] = hv;
    }
  }
#pragma unroll
  for (int rr = 0; rr < 4; ++rr)
    hstate[((long)b * Nn + i0 + w * 4 + rr) * Hh + lane] = h_reg[rr];
}

// ---------------------------------------------------------------------------
// MISC: blocks < Bsz*Nn: decoder adjacencies A1d[i][j], A2d[i][j] (row layout).
//       blocks >= Bsz*Nn: dec0 (x0 = mlp(h)).
// ---------------------------------------------------------------------------
__global__ __launch_bounds__(256) void k_misc(
    const float* __restrict__ hw, const float2* __restrict__ pk,
    const float* __restrict__ d23, const float* __restrict__ e23,
    float* __restrict__ A1d, float* __restrict__ A2d,
    const float* __restrict__ hstate,
    const float* __restrict__ wm1T, const float* __restrict__ bm1,
    const float* __restrict__ wm2T, const float* __restrict__ bm2,
    float* __restrict__ xnext) {
  __shared__ float h_lds[16][Hh];
  __shared__ float u_lds[16][M1];
  int tid = threadIdx.x;
  if (blockIdx.x < Bsz * Nn) {
    int b = blockIdx.x >> 8;
    int i = blockIdx.x & 255;
    int j = tid;
    float spd = hw[(b * Tt + (Tt - 1)) * Fw + 2];
    float rad = hw[(b * Tt + (Tt - 1)) * Fw + 1] * DEG2RAD;
    float cr = cosf(rad), sr = sinf(rad);
    const float* drow = d23 + b * Nn;
    const float* erow = e23 + b * Nn;
    float2 pv = pk[i * Nn + j];
    float val = spd * (pv.x * cr + pv.y * sr);
    float dlt = (j == i) ? 1.f : 0.f;
    float wout = fmaxf(val, 0.f);
    float win  = (j == i) ? wout : fmaxf(-val, 0.f);
    A1d[((long)b * Nn + i) * Nn + j] = drow[i] * (wout + dlt) * drow[j];
    A2d[((long)b * Nn + i) * Nn + j] = erow[i] * (win + dlt) * erow[j];
    return;
  }
  int r0 = (blockIdx.x - Bsz * Nn) * 16;
#pragma unroll
  for (int c = 0; c < 4; ++c) {
    int idx = tid + c * 256;
    h_lds[idx >> 6][idx & 63] = hstate[(long)r0 * Hh + idx];
  }
  __syncthreads();
#pragma unroll
  for (int rep = 0; rep < 2; ++rep) {
    int idx = tid + rep * 256;
    int row = idx >> 5, m = idx & 31;
    float um = bm1[m];
    for (int k = 0; k < Hh; ++k) um += wm1T[k * M1 + m] * h_lds[row][k];
    u_lds[row][m] = fmaxf(um, 0.f);
  }
  __syncthreads();
  if (tid < 16 * Fp) {
    int row = tid / Fp, f = tid % Fp;
    float pf = bm2[f];
#pragma unroll
    for (int m = 0; m < M1; ++m) pf += wm2T[m * Fp + f] * u_lds[row][m];
    xnext[(r0 + row) * Fp + f] = pf;
  }
}

// ---------------------------------------------------------------------------
// Ddec A: gconv1 for decoder. 512 blocks (8 rows each) -> 2+ blocks/CU.
// ---------------------------------------------------------------------------
__global__ __launch_bounds__(256) void k_dstep_A(
    const float* __restrict__ xb, const float* __restrict__ A1d,
    const float* __restrict__ wgc1, const float* __restrict__ bgc1,
    float* __restrict__ h1d) {
  __shared__ float x_lds[Nn * Fp];
  int b = blockIdx.x >> 5;
  int i0 = (blockIdx.x & 31) * 8;
  int tid = threadIdx.x, w = tid >> 6, lane = tid & 63;
  const float* xsrc = xb + (long)b * Nn * Fp;
#pragma unroll
  for (int c = 0; c < 6; ++c) x_lds[tid + 256 * c] = xsrc[tid + 256 * c];
  __syncthreads();
#pragma unroll
  for (int rr = 0; rr < 2; ++rr) {
    int i = i0 + w * 2 + rr;
    const float* arow = A1d + ((long)b * Nn + i) * Nn;
    float acc[Fp] = {0.f, 0.f, 0.f, 0.f, 0.f, 0.f};
#pragma unroll
    for (int c = 0; c < 4; ++c) {
      int j = lane + 64 * c;
      float wt = arow[j];
#pragma unroll
      for (int f = 0; f < Fp; ++f) acc[f] += wt * x_lds[j * Fp + f];
    }
#pragma unroll
    for (int f = 0; f < Fp; ++f) {
#pragma unroll
      for (int off = 32; off; off >>= 1) acc[f] += __shfl_xor(acc[f], off);
    }
    float hv = bgc1[lane];
#pragma unroll
    for (int f = 0; f < Fp; ++f) hv += wgc1[lane * Fp + f] * acc[f];
    h1d[((long)b * Nn + i) * Hh + lane] = fmaxf(hv, 0.f);
  }
}

// ---------------------------------------------------------------------------
// Ddec B: gconv2 + W2 + GRU + MLP. 512 blocks (8 rows each), ~29KB LDS ->
// 2 blocks/CU co-resident for latency overlap.
// ---------------------------------------------------------------------------
__global__ __launch_bounds__(256) void k_dstep_B(
    const float* __restrict__ A2d, const float* __restrict__ h1d,
    const float* __restrict__ wgc2T, const float* __restrict__ bgc2,
    const float4* __restrict__ wihP, const float4* __restrict__ whhP,
    const float* __restrict__ bih, const float* __restrict__ bhh,
    float* __restrict__ hstate,
    const float* __restrict__ wm1T, const float* __restrict__ bm1,
    const float* __restrict__ wm2T, const float* __restrict__ bm2,
    float* __restrict__ outp, float* __restrict__ xnext, int p) {
  __shared__ __align__(16) float wvT[Nn * 12];   // 12KB (8 used + 4 pad)
  __shared__ float red[4][8][Hh];                // 8KB
  __shared__ float y2[8][Hh];
  __shared__ float sf_s[8][Hh];
  __shared__ float h_s[8][Hh];
  __shared__ float hn_lds[8][Hh];
  __shared__ float u_lds[8][M1];
  int b = blockIdx.x >> 5;
  int i0 = (blockIdx.x & 31) * 8;
  int tid = threadIdx.x, w = tid >> 6, lane = tid & 63;

#pragma unroll
  for (int r = 0; r < 8; ++r)
    wvT[tid * 12 + r] = A2d[((long)b * Nn + i0 + r) * Nn + tid];
  float hp_reg[2];
#pragma unroll
  for (int rr = 0; rr < 2; ++rr) {
    hp_reg[rr] = hstate[((long)b * Nn + i0 + w * 2 + rr) * Hh + lane];
    h_s[w * 2 + rr][lane] = hp_reg[rr];
  }
  __syncthreads();

  float acc[8];
#pragma unroll
  for (int r = 0; r < 8; ++r) acc[r] = 0.f;
  const float* h1b = h1d + (long)b * Nn * Hh;
#pragma unroll 4
  for (int jj = 0; jj < 64; ++jj) {
    int j = w * 64 + jj;
    float hv = h1b[j * Hh + lane];
    float4 w0 = *(const float4*)&wvT[j * 12];
    float4 w1 = *(const float4*)&wvT[j * 12 + 4];
    acc[0] += w0.x * hv; acc[1] += w0.y * hv; acc[2] += w0.z * hv; acc[3] += w0.w * hv;
    acc[4] += w1.x * hv; acc[5] += w1.y * hv; acc[6] += w1.z * hv; acc[7] += w1.w * hv;
  }
#pragma unroll
  for (int r = 0; r < 8; ++r) red[w][r][lane] = acc[r];
  __syncthreads();
#pragma unroll
  for (int rr = 0; rr < 2; ++rr) {
    int r = w * 2 + rr;
    y2[r][lane] = red[0][r][lane] + red[1][r][lane] + red[2][r][lane] + red[3][r][lane];
  }
  {
    float a0 = bgc2[lane], a1 = a0;
    for (int k = 0; k < Hh; ++k) {
      float wk = wgc2T[k * Hh + lane];
      a0 += wk * y2[w * 2 + 0][k];
      a1 += wk * y2[w * 2 + 1][k];
    }
    sf_s[w * 2 + 0][lane] = fmaxf(a0, 0.f);
    sf_s[w * 2 + 1][lane] = fmaxf(a1, 0.f);
  }

  float hn_reg[2];
  {
    float bi_r = bih[lane], bi_z = bih[64 + lane], bi_n = bih[128 + lane];
    float bh_r = bhh[lane], bh_z = bhh[64 + lane], bh_n = bhh[128 + lane];
    float gir[2], giz[2], gin[2], ghr[2], ghz[2], ghn[2];
#pragma unroll
    for (int rr = 0; rr < 2; ++rr) {
      gir[rr] = bi_r; giz[rr] = bi_z; gin[rr] = bi_n;
      ghr[rr] = bh_r; ghz[rr] = bh_z; ghn[rr] = bh_n;
    }
#pragma unroll 4
    for (int kb = 0; kb < 16; ++kb) {
      int k0 = kb * 4;
      float4 wi[4], wh[4];
#pragma unroll
      for (int q = 0; q < 4; ++q) {
        wi[q] = wihP[(k0 + q) * 64 + lane];
        wh[q] = whhP[(k0 + q) * 64 + lane];
      }
#pragma unroll
      for (int rr = 0; rr < 2; ++rr) {
        const float4 s4 = *(const float4*)&sf_s[w * 2 + rr][k0];
        const float4 h4 = *(const float4*)&h_s[w * 2 + rr][k0];
        gir[rr] += s4.x * wi[0].x + s4.y * wi[1].x + s4.z * wi[2].x + s4.w * wi[3].x;
        giz[rr] += s4.x * wi[0].y + s4.y * wi[1].y + s4.z * wi[2].y + s4.w * wi[3].y;
        gin[rr] += s4.x * wi[0].z + s4.y * wi[1].z + s4.z * wi[2].z + s4.w * wi[3].z;
        ghr[rr] += h4.x * wh[0].x + h4.y * wh[1].x + h4.z * wh[2].x + h4.w * wh[3].x;
        ghz[rr] += h4.x * wh[0].y + h4.y * wh[1].y + h4.z * wh[2].y + h4.w * wh[3].y;
        ghn[rr] += h4.x * wh[0].z + h4.y * wh[1].z + h4.z * wh[2].z + h4.w * wh[3].z;
      }
    }
#pragma unroll
    for (int rr = 0; rr < 2; ++rr) {
      float rg = 1.f / (1.f + expf(-(gir[rr] + ghr[rr])));
      float zg = 1.f / (1.f + expf(-(giz[rr] + ghz[rr])));
      float ng = tanhf(gin[rr] + rg * ghn[rr]);
      hn_reg[rr] = (1.f - zg) * ng + zg * hp_reg[rr];
      hstate[((long)b * Nn + i0 + w * 2 + rr) * Hh + lane] = hn_reg[rr];
      hn_lds[w * 2 + rr][lane] = hn_reg[rr];
    }
  }
  __syncthreads();
  {
    int row = tid >> 5, m = tid & 31;
    float um = bm1[m];
    for (int k = 0; k < Hh; ++k) um += wm1T[k * M1 + m] * hn_lds[row][k];
    u_lds[row][m] = fmaxf(um, 0.f);
  }
  __syncthreads();
  if (tid < 8 * Fp) {
    int row = tid / Fp, f = tid - row * Fp;
    float pf = bm2[f];
#pragma unroll
    for (int m = 0; m < M1; ++m) pf += wm2T[m * Fp + f] * u_lds[row][m];
    int i = i0 + row;
    outp[(((long)b * PredL + p) * Nn + i) * Fp + f] = pf;
    xnext[((long)b * Nn + i) * Fp + f] = pf;
  }
}

// ---------------------------------------------------------------------------
extern "C" void kernel_launch(void* const* d_in, const int* in_sizes, int n_in,
                              void* d_out, int out_size, void* d_ws, size_t ws_size,
                              hipStream_t stream) {
  const float* hp     = (const float*)d_in[0];
  const float* hw     = (const float*)d_in[1];
  const float* adj    = (const float*)d_in[2];
  const float* coords = (const float*)d_in[3];
  const float* wgc1   = (const float*)d_in[4];
  const float* bgc1   = (const float*)d_in[5];
  const float* wgc2   = (const float*)d_in[6];
  const float* bgc2   = (const float*)d_in[7];
  const float* wih    = (const float*)d_in[8];
  const float* whh    = (const float*)d_in[9];
  const float* bih    = (const float*)d_in[10];
  const float* bhh    = (const float*)d_in[11];
  const float* wm1    = (const float*)d_in[12];
  const float* bm1    = (const float*)d_in[13];
  const float* wm2    = (const float*)d_in[14];
  const float* bm2    = (const float*)d_in[15];
  float* out = (float*)d_out;

  float* w = (float*)d_ws;
  float2* pk    = (float2*)w; w += Nn * Nn * 2;
  float* d23    = w; w += Bsz * Nn;
  float* e23    = w; w += Bsz * Nn;
  float* hstate = w; w += Bsz * Nn * Hh;
  float* sf_all = w; w += (long)Tt * Bsz * Nn * Hh;
  float* gi_ch  = w; w += (long)TCHUNK * Bsz * Nn * 3 * 64;
  float* h1d    = w; w += Bsz * Nn * Hh;
  float* xb0    = w; w += Bsz * Nn * Fp;
  float* xb1    = w; w += Bsz * Nn * Fp;
  float* A1d    = w; w += Bsz * Nn * Nn;
  float* A2d    = w; w += Bsz * Nn * Nn;
  float* wgc2T  = w; w += Hh * Hh;
  float* wm1T   = w; w += Hh * M1;
  float* wm2T   = w; w += M1 * Fp;
  float4* wihP  = (float4*)w; w += Hh * 64 * 4;
  float4* whhP  = (float4*)w; w += Hh * 64 * 4;

  k_prep<<<Nn + 1, 256, 0, stream>>>(coords, adj, wgc2, wih, whh, wm1, wm2,
                                     pk, wgc2T, wm1T, wm2T, wihP, whhP);
  k_enc<<<Tt * Bsz * 2, 256, 0, stream>>>(pk, hp, hw, wgc1, bgc1, wgc2T, bgc2,
                                          sf_all, d23, e23);
  for (int s = 0; s < Tt / TCHUNK; ++s) {
    int t0 = s * TCHUNK;
    k_gi<<<(TCHUNK * Bsz * Nn) / 64, 256, 0, stream>>>(sf_all, wihP, bih,
                                                       gi_ch, t0);
    k_gru_scan4<<<Bsz * 16, 256, 0, stream>>>(gi_ch, whhP, bhh, hstate,
                                              t0, TCHUNK);
  }
  k_misc<<<Bsz * Nn + Bsz * Nn / 16, 256, 0, stream>>>(
      hw, pk, d23, e23, A1d, A2d, hstate, wm1T, bm1, wm2T, bm2, xb0);

  for (int p = 0; p < PredL; ++p) {
    float* xin  = (p & 1) ? xb1 : xb0;
    float* xout = (p & 1) ? xb0 : xb1;
    k_dstep_A<<<Bsz * 32, 256, 0, stream>>>(xin, A1d, wgc1, bgc1, h1d);
    k_dstep_B<<<Bsz * 32, 256, 0, stream>>>(
        A2d, h1d, wgc2T, bgc2, wihP, whhP, bih, bhh, hstate,
        wm1T, bm1, wm2T, bm2, out, xout, p);
  }
}

// Round 17
// 659.931 us; speedup vs baseline: 1.1363x; 1.1363x over previous
//
#include <hip/hip_runtime.h>
#include <math.h>

#define Bsz 16
#define Tt 24
#define Nn 256
#define Fp 6
#define Hh 64
#define PredL 12
#define Fw 4
#define M1 32
#define TCHUNK 12
#define DEG2RAD 0.017453292519943295f
#define IDX2(t, b) ((t) * Bsz + (b))

// ---------------------------------------------------------------------------
// P0+PT: blocks 0..255 build packed pk[i][j] = {Ac,As}; block 256 repacks
// weights (wgc2T[k][g], wm1T, wm2T, wihP/whhP float4 {r,z,n,0} per [k][lane]).
// ---------------------------------------------------------------------------
__global__ __launch_bounds__(256) void k_prep(
    const float* __restrict__ coords, const float* __restrict__ adj,
    const float* __restrict__ wgc2, const float* __restrict__ wih,
    const float* __restrict__ whh,  const float* __restrict__ wm1,
    const float* __restrict__ wm2,
    float2* __restrict__ pk,
    float* __restrict__ wgc2T, float* __restrict__ wm1T, float* __restrict__ wm2T,
    float4* __restrict__ wihP, float4* __restrict__ whhP) {
  int tid = threadIdx.x;
  if (blockIdx.x < Nn) {
    int i = blockIdx.x;
    int j = tid;
    float dx = coords[2 * j]     - coords[2 * i];
    float dy = coords[2 * j + 1] - coords[2 * i + 1];
    float ang = atan2f(dy, dx);
    float a = adj[i * Nn + j];
    pk[i * Nn + j] = make_float2(a * cosf(ang), a * sinf(ang));
    return;
  }
  for (int idx = tid; idx < Hh * Hh; idx += 256) {
    int g = idx / Hh, k = idx % Hh;
    wgc2T[k * Hh + g] = wgc2[g * Hh + k];
  }
  for (int idx = tid; idx < M1 * Hh; idx += 256) {
    int m = idx / Hh, k = idx % Hh;
    wm1T[k * M1 + m] = wm1[m * Hh + k];
  }
  for (int idx = tid; idx < Fp * M1; idx += 256) {
    int f = idx / M1, m = idx % M1;
    wm2T[m * Fp + f] = wm2[f * M1 + m];
  }
  for (int idx = tid; idx < Hh * 64; idx += 256) {
    int k = idx >> 6, lane = idx & 63;
    wihP[idx] = make_float4(wih[(0 * 64 + lane) * Hh + k],
                            wih[(1 * 64 + lane) * Hh + k],
                            wih[(2 * 64 + lane) * Hh + k], 0.f);
    whhP[idx] = make_float4(whh[(0 * 64 + lane) * Hh + k],
                            whh[(1 * 64 + lane) * Hh + k],
                            whh[(2 * 64 + lane) * Hh + k], 0.f);
  }
}

// ---------------------------------------------------------------------------
// E: fused encoder (measured-best 153us form): deg + gconv1 + gconv2 + W2
// -> sf_all. One block per (t,b), 256 threads, thread = row.
// ---------------------------------------------------------------------------
__global__ __launch_bounds__(256) void k_enc(
    const float2* __restrict__ pk, const float* __restrict__ hp,
    const float* __restrict__ hw,
    const float* __restrict__ wgc1, const float* __restrict__ bgc1,
    const float* __restrict__ wgc2T, const float* __restrict__ bgc2,
    float* __restrict__ sf_all,
    float* __restrict__ d23, float* __restrict__ e23) {
  __shared__ float d_lds[Nn];
  __shared__ float e_lds[Nn];
  __shared__ __align__(16) float u_s[Nn * 8];     // 8KB
  __shared__ __align__(16) float h1_s[Nn * 68];   // 69.6KB
  int tb = blockIdx.x, t = tb / Bsz, b = tb % Bsz;
  int tid = threadIdx.x;
  int i = tid;
  float spd = hw[(b * Tt + t) * Fw + 2];
  float rad = hw[(b * Tt + t) * Fw + 1] * DEG2RAD;
  float scr = spd * cosf(rad), ssr = spd * sinf(rad);

  // ---- pass 0: degrees (from column i of pk) ----
  {
    float rs = 0.f, cs = 0.f;
#pragma unroll 4
    for (int j = 0; j < Nn; ++j) {
      float2 pv = pk[j * Nn + i];
      float v = pv.x * scr + pv.y * ssr;   // V(j,i)
      cs += fmaxf(v, 0.f);
      rs += fmaxf(-v, 0.f);
    }
    float2 pd = pk[i * Nn + i];
    float vii = pd.x * scr + pd.y * ssr;
    rs += vii;  // diag fix
    float di = 1.f / (sqrtf(rs + 1.f) + 1e-6f);
    float ei = 1.f / (sqrtf(cs + 1.f) + 1e-6f);
    d_lds[i] = di; e_lds[i] = ei;
    if (t == Tt - 1) { d23[b * Nn + i] = di; e23[b * Nn + i] = ei; }
  }
  __syncthreads();

  // ---- stage u = d_j * x ----
  {
    const float* xsrc = hp + (long)(b * Tt + t) * Nn * Fp;
    for (int idx = tid; idx < Nn * Fp; idx += 256) {
      int j = idx / Fp, f = idx - j * Fp;
      u_s[j * 8 + f] = d_lds[j] * xsrc[idx];
    }
    u_s[tid * 8 + 6] = 0.f;
    u_s[tid * 8 + 7] = 0.f;
  }
  __syncthreads();

  // ---- pass 1: gconv1 for row i; e-scaled h1 row -> LDS ----
  {
    float a0 = 0.f, a1 = 0.f, a2 = 0.f, a3 = 0.f, a4 = 0.f, a5 = 0.f;
#pragma unroll 2
    for (int j = 0; j < Nn; ++j) {
      float2 pv = pk[j * Nn + i];
      float v = pv.x * scr + pv.y * ssr;
      float w = fmaxf(-v, 0.f);            // wout[i][j], wrong on diag
      float4 ul = *(const float4*)&u_s[j * 8];
      float4 uh = *(const float4*)&u_s[j * 8 + 4];
      a0 += w * ul.x; a1 += w * ul.y; a2 += w * ul.z;
      a3 += w * ul.w; a4 += w * uh.x; a5 += w * uh.y;
    }
    float2 pd = pk[i * Nn + i];
    float vii = pd.x * scr + pd.y * ssr;
    float di = d_lds[i], ei = e_lds[i];
    float c1 = vii + 1.f;  // diag fix + identity
    float y0 = di * (a0 + c1 * u_s[i * 8 + 0]);
    float y1 = di * (a1 + c1 * u_s[i * 8 + 1]);
    float y2 = di * (a2 + c1 * u_s[i * 8 + 2]);
    float y3 = di * (a3 + c1 * u_s[i * 8 + 3]);
    float y4 = di * (a4 + c1 * u_s[i * 8 + 4]);
    float y5 = di * (a5 + c1 * u_s[i * 8 + 5]);
#pragma unroll
    for (int g4 = 0; g4 < 16; ++g4) {
      float4 hv;
#pragma unroll
      for (int q = 0; q < 4; ++q) {
        int g = g4 * 4 + q;
        float v2 = bgc1[g] + wgc1[g * Fp + 0] * y0 + wgc1[g * Fp + 1] * y1 +
                   wgc1[g * Fp + 2] * y2 + wgc1[g * Fp + 3] * y3 +
                   wgc1[g * Fp + 4] * y4 + wgc1[g * Fp + 5] * y5;
        ((float*)&hv)[q] = fmaxf(v2, 0.f) * ei;
      }
      *(float4*)&h1_s[i * 68 + g4 * 4] = hv;
    }
  }
  __syncthreads();

  // ---- pass 2: z[i][g] = e_i * sum_j (win+I)[i][j] h1e[j] ----
  float z[64];
#pragma unroll
  for (int k = 0; k < 64; ++k) z[k] = 0.f;
#pragma unroll 2
  for (int j = 0; j < Nn; ++j) {
    float2 pv = pk[j * Nn + i];
    float v = pv.x * scr + pv.y * ssr;     // V(j,i)
    float wf = fmaxf(v, 0.f) + ((j == i) ? 1.f : 0.f);
#pragma unroll
    for (int g4 = 0; g4 < 16; ++g4) {
      float4 h4 = *(const float4*)&h1_s[j * 68 + g4 * 4];
      z[g4 * 4 + 0] += wf * h4.x;
      z[g4 * 4 + 1] += wf * h4.y;
      z[g4 * 4 + 2] += wf * h4.z;
      z[g4 * 4 + 3] += wf * h4.w;
    }
  }
  {
    float ei = e_lds[i];
#pragma unroll
    for (int k = 0; k < 64; ++k) z[k] *= ei;
  }
  __syncthreads();   // h1_s free; reuse for sf staging

  // ---- W2 + relu -> staged in h1_s, then coalesced store ----
#pragma unroll
  for (int c = 0; c < 4; ++c) {
    float s[16];
#pragma unroll
    for (int q = 0; q < 16; ++q) s[q] = bgc2[c * 16 + q];
#pragma unroll
    for (int k = 0; k < 64; ++k) {
      float zk = z[k];
#pragma unroll
      for (int q = 0; q < 16; ++q) s[q] += wgc2T[k * Hh + c * 16 + q] * zk;
    }
#pragma unroll
    for (int q4 = 0; q4 < 4; ++q4) {
      float4 sv = make_float4(fmaxf(s[q4 * 4 + 0], 0.f), fmaxf(s[q4 * 4 + 1], 0.f),
                              fmaxf(s[q4 * 4 + 2], 0.f), fmaxf(s[q4 * 4 + 3], 0.f));
      *(float4*)&h1_s[i * 68 + c * 16 + q4 * 4] = sv;
    }
  }
  __syncthreads();
  long base = (long)IDX2(t, b) * Nn * Hh;
  for (int idx = tid; idx < Nn * 16; idx += 256) {
    int j = idx >> 4, g4 = idx & 15;
    *(float4*)&sf_all[base + j * Hh + g4 * 4] = *(const float4*)&h1_s[j * 68 + g4 * 4];
  }
}

// ---------------------------------------------------------------------------
// GI: gi = sf @ W_ih^T + b_ih for TCHUNK timesteps (16 rows/wave, VALU-bound)
// ---------------------------------------------------------------------------
__global__ __launch_bounds__(256) void k_gi(
    const float* __restrict__ sf_all, const float4* __restrict__ wihP,
    const float* __restrict__ bih, float* __restrict__ gi, int t0) {
  __shared__ float sf_c[4][16][64];
  int tid = threadIdx.x, w = tid >> 6, lane = tid & 63;
  int rowc0 = blockIdx.x * 64 + w * 16;
  long rowg0 = (long)t0 * (Bsz * Nn) + rowc0;
#pragma unroll
  for (int rr = 0; rr < 16; ++rr)
    sf_c[w][rr][lane] = sf_all[(rowg0 + rr) * Hh + lane];
  float bi_r = bih[lane], bi_z = bih[64 + lane], bi_n = bih[128 + lane];
  float ar[16], az[16], an[16];
#pragma unroll
  for (int rr = 0; rr < 16; ++rr) { ar[rr] = bi_r; az[rr] = bi_z; an[rr] = bi_n; }
#pragma unroll 2
  for (int kb = 0; kb < 16; ++kb) {
    int k0 = kb * 4;
    float4 wi0 = wihP[(k0 + 0) * 64 + lane];
    float4 wi1 = wihP[(k0 + 1) * 64 + lane];
    float4 wi2 = wihP[(k0 + 2) * 64 + lane];
    float4 wi3 = wihP[(k0 + 3) * 64 + lane];
#pragma unroll
    for (int rr = 0; rr < 16; ++rr) {
      const float4 s4 = *(const float4*)&sf_c[w][rr][k0];
      ar[rr] += s4.x * wi0.x + s4.y * wi1.x + s4.z * wi2.x + s4.w * wi3.x;
      az[rr] += s4.x * wi0.y + s4.y * wi1.y + s4.z * wi2.y + s4.w * wi3.y;
      an[rr] += s4.x * wi0.z + s4.y * wi1.z + s4.z * wi2.z + s4.w * wi3.z;
    }
  }
#pragma unroll
  for (int rr = 0; rr < 16; ++rr) {
    long rowc = rowc0 + rr;
    gi[(rowc * 3 + 0) * 64 + lane] = ar[rr];
    gi[(rowc * 3 + 1) * 64 + lane] = az[rr];
    gi[(rowc * 3 + 2) * 64 + lane] = an[rr];
  }
}

// ---------------------------------------------------------------------------
// GRU scan over one chunk (gh only; whh streamed; h broadcast via LDS rows)
// ---------------------------------------------------------------------------
__global__ __launch_bounds__(256) void k_gru_scan4(
    const float* __restrict__ gi, const float4* __restrict__ whhP,
    const float* __restrict__ bhh, float* __restrict__ hstate,
    int t0, int nt) {
  __shared__ float h_s[16][64];
  int b = blockIdx.x >> 4;
  int i0 = (blockIdx.x & 15) * 16;
  int tid = threadIdx.x, w = tid >> 6, lane = tid & 63;
  float bh_r = bhh[lane], bh_z = bhh[64 + lane], bh_n = bhh[128 + lane];
  float h_reg[4];
#pragma unroll
  for (int rr = 0; rr < 4; ++rr) {
    float hv = (t0 == 0) ? 0.f
                         : hstate[((long)b * Nn + i0 + w * 4 + rr) * Hh + lane];
    h_reg[rr] = hv;
    h_s[w * 4 + rr][lane] = hv;
  }
  for (int tl = 0; tl < nt; ++tl) {
    long rbase = ((long)tl * Bsz + b) * Nn + i0 + w * 4;
    float gr[4], gz[4], gn[4], hr[4], hz[4], hn[4];
#pragma unroll
    for (int rr = 0; rr < 4; ++rr) {
      gr[rr] = gi[((rbase + rr) * 3 + 0) * 64 + lane];
      gz[rr] = gi[((rbase + rr) * 3 + 1) * 64 + lane];
      gn[rr] = gi[((rbase + rr) * 3 + 2) * 64 + lane];
      hr[rr] = bh_r; hz[rr] = bh_z; hn[rr] = bh_n;
    }
#pragma unroll 4
    for (int kb = 0; kb < 16; ++kb) {
      int k0 = kb * 4;
      float4 wh0 = whhP[(k0 + 0) * 64 + lane];
      float4 wh1 = whhP[(k0 + 1) * 64 + lane];
      float4 wh2 = whhP[(k0 + 2) * 64 + lane];
      float4 wh3 = whhP[(k0 + 3) * 64 + lane];
#pragma unroll
      for (int rr = 0; rr < 4; ++rr) {
        const float4 h4 = *(const float4*)&h_s[w * 4 + rr][k0];
        hr[rr] += h4.x * wh0.x + h4.y * wh1.x + h4.z * wh2.x + h4.w * wh3.x;
        hz[rr] += h4.x * wh0.y + h4.y * wh1.y + h4.z * wh2.y + h4.w * wh3.y;
        hn[rr] += h4.x * wh0.z + h4.y * wh1.z + h4.z * wh2.z + h4.w * wh3.z;
      }
    }
#pragma unroll
    for (int rr = 0; rr < 4; ++rr) {
      float rg = 1.f / (1.f + expf(-(gr[rr] + hr[rr])));
      float zg = 1.f / (1.f + expf(-(gz[rr] + hz[rr])));
      float ng = tanhf(gn[rr] + rg * hn[rr]);
      float hv = (1.f - zg) * ng + zg * h_reg[rr];
      h_reg[rr] = hv;
      h_s[w * 4 + rr][lane] = hv;
    }
  }
#pragma unroll
  for (int rr = 0; rr < 4; ++rr)
    hstate[((long)b * Nn + i0 + w * 4 + rr) * Hh + lane] = h_reg[rr];
}

// ---------------------------------------------------------------------------
// MISC: blocks < Bsz*Nn: decoder adjacencies A1d[i][j], A2d[i][j] (row layout).
//       blocks >= Bsz*Nn: dec0 (x0 = mlp(h)).
// ---------------------------------------------------------------------------
__global__ __launch_bounds__(256) void k_misc(
    const float* __restrict__ hw, const float2* __restrict__ pk,
    const float* __restrict__ d23, const float* __restrict__ e23,
    float* __restrict__ A1d, float* __restrict__ A2d,
    const float* __restrict__ hstate,
    const float* __restrict__ wm1T, const float* __restrict__ bm1,
    const float* __restrict__ wm2T, const float* __restrict__ bm2,
    float* __restrict__ xnext) {
  __shared__ float h_lds[16][Hh];
  __shared__ float u_lds[16][M1];
  int tid = threadIdx.x;
  if (blockIdx.x < Bsz * Nn) {
    int b = blockIdx.x >> 8;
    int i = blockIdx.x & 255;
    int j = tid;
    float spd = hw[(b * Tt + (Tt - 1)) * Fw + 2];
    float rad = hw[(b * Tt + (Tt - 1)) * Fw + 1] * DEG2RAD;
    float cr = cosf(rad), sr = sinf(rad);
    const float* drow = d23 + b * Nn;
    const float* erow = e23 + b * Nn;
    float2 pv = pk[i * Nn + j];
    float val = spd * (pv.x * cr + pv.y * sr);
    float dlt = (j == i) ? 1.f : 0.f;
    float wout = fmaxf(val, 0.f);
    float win  = (j == i) ? wout : fmaxf(-val, 0.f);
    A1d[((long)b * Nn + i) * Nn + j] = drow[i] * (wout + dlt) * drow[j];
    A2d[((long)b * Nn + i) * Nn + j] = erow[i] * (win + dlt) * erow[j];
    return;
  }
  int r0 = (blockIdx.x - Bsz * Nn) * 16;
#pragma unroll
  for (int c = 0; c < 4; ++c) {
    int idx = tid + c * 256;
    h_lds[idx >> 6][idx & 63] = hstate[(long)r0 * Hh + idx];
  }
  __syncthreads();
#pragma unroll
  for (int rep = 0; rep < 2; ++rep) {
    int idx = tid + rep * 256;
    int row = idx >> 5, m = idx & 31;
    float um = bm1[m];
    for (int k = 0; k < Hh; ++k) um += wm1T[k * M1 + m] * h_lds[row][k];
    u_lds[row][m] = fmaxf(um, 0.f);
  }
  __syncthreads();
  if (tid < 16 * Fp) {
    int row = tid / Fp, f = tid % Fp;
    float pf = bm2[f];
#pragma unroll
    for (int m = 0; m < M1; ++m) pf += wm2T[m * Fp + f] * u_lds[row][m];
    xnext[(r0 + row) * Fp + f] = pf;
  }
}

// ---------------------------------------------------------------------------
// Ddec A: gconv1 for decoder. 512 blocks (8 rows each) -> 2+ blocks/CU.
// ---------------------------------------------------------------------------
__global__ __launch_bounds__(256) void k_dstep_A(
    const float* __restrict__ xb, const float* __restrict__ A1d,
    const float* __restrict__ wgc1, const float* __restrict__ bgc1,
    float* __restrict__ h1d) {
  __shared__ float x_lds[Nn * Fp];
  int b = blockIdx.x >> 5;
  int i0 = (blockIdx.x & 31) * 8;
  int tid = threadIdx.x, w = tid >> 6, lane = tid & 63;
  const float* xsrc = xb + (long)b * Nn * Fp;
#pragma unroll
  for (int c = 0; c < 6; ++c) x_lds[tid + 256 * c] = xsrc[tid + 256 * c];
  __syncthreads();
#pragma unroll
  for (int rr = 0; rr < 2; ++rr) {
    int i = i0 + w * 2 + rr;
    const float* arow = A1d + ((long)b * Nn + i) * Nn;
    float acc[Fp] = {0.f, 0.f, 0.f, 0.f, 0.f, 0.f};
#pragma unroll
    for (int c = 0; c < 4; ++c) {
      int j = lane + 64 * c;
      float wt = arow[j];
#pragma unroll
      for (int f = 0; f < Fp; ++f) acc[f] += wt * x_lds[j * Fp + f];
    }
#pragma unroll
    for (int f = 0; f < Fp; ++f) {
#pragma unroll
      for (int off = 32; off; off >>= 1) acc[f] += __shfl_xor(acc[f], off);
    }
    float hv = bgc1[lane];
#pragma unroll
    for (int f = 0; f < Fp; ++f) hv += wgc1[lane * Fp + f] * acc[f];
    h1d[((long)b * Nn + i) * Hh + lane] = fmaxf(hv, 0.f);
  }
}

// ---------------------------------------------------------------------------
// Ddec B: gconv2 + W2 + GRU + MLP. 512 blocks (8 rows each), ~29KB LDS ->
// 2 blocks/CU co-resident for latency overlap.
// ---------------------------------------------------------------------------
__global__ __launch_bounds__(256) void k_dstep_B(
    const float* __restrict__ A2d, const float* __restrict__ h1d,
    const float* __restrict__ wgc2T, const float* __restrict__ bgc2,
    const float4* __restrict__ wihP, const float4* __restrict__ whhP,
    const float* __restrict__ bih, const float* __restrict__ bhh,
    float* __restrict__ hstate,
    const float* __restrict__ wm1T, const float* __restrict__ bm1,
    const float* __restrict__ wm2T, const float* __restrict__ bm2,
    float* __restrict__ outp, float* __restrict__ xnext, int p) {
  __shared__ __align__(16) float wvT[Nn * 12];   // 12KB (8 used + 4 pad)
  __shared__ float red[4][8][Hh];                // 8KB
  __shared__ float y2[8][Hh];
  __shared__ float sf_s[8][Hh];
  __shared__ float h_s[8][Hh];
  __shared__ float hn_lds[8][Hh];
  __shared__ float u_lds[8][M1];
  int b = blockIdx.x >> 5;
  int i0 = (blockIdx.x & 31) * 8;
  int tid = threadIdx.x, w = tid >> 6, lane = tid & 63;

#pragma unroll
  for (int r = 0; r < 8; ++r)
    wvT[tid * 12 + r] = A2d[((long)b * Nn + i0 + r) * Nn + tid];
  float hp_reg[2];
#pragma unroll
  for (int rr = 0; rr < 2; ++rr) {
    hp_reg[rr] = hstate[((long)b * Nn + i0 + w * 2 + rr) * Hh + lane];
    h_s[w * 2 + rr][lane] = hp_reg[rr];
  }
  __syncthreads();

  float acc[8];
#pragma unroll
  for (int r = 0; r < 8; ++r) acc[r] = 0.f;
  const float* h1b = h1d + (long)b * Nn * Hh;
#pragma unroll 4
  for (int jj = 0; jj < 64; ++jj) {
    int j = w * 64 + jj;
    float hv = h1b[j * Hh + lane];
    float4 w0 = *(const float4*)&wvT[j * 12];
    float4 w1 = *(const float4*)&wvT[j * 12 + 4];
    acc[0] += w0.x * hv; acc[1] += w0.y * hv; acc[2] += w0.z * hv; acc[3] += w0.w * hv;
    acc[4] += w1.x * hv; acc[5] += w1.y * hv; acc[6] += w1.z * hv; acc[7] += w1.w * hv;
  }
#pragma unroll
  for (int r = 0; r < 8; ++r) red[w][r][lane] = acc[r];
  __syncthreads();
#pragma unroll
  for (int rr = 0; rr < 2; ++rr) {
    int r = w * 2 + rr;
    y2[r][lane] = red[0][r][lane] + red[1][r][lane] + red[2][r][lane] + red[3][r][lane];
  }
  {
    float a0 = bgc2[lane], a1 = a0;
    for (int k = 0; k < Hh; ++k) {
      float wk = wgc2T[k * Hh + lane];
      a0 += wk * y2[w * 2 + 0][k];
      a1 += wk * y2[w * 2 + 1][k];
    }
    sf_s[w * 2 + 0][lane] = fmaxf(a0, 0.f);
    sf_s[w * 2 + 1][lane] = fmaxf(a1, 0.f);
  }

  float hn_reg[2];
  {
    float bi_r = bih[lane], bi_z = bih[64 + lane], bi_n = bih[128 + lane];
    float bh_r = bhh[lane], bh_z = bhh[64 + lane], bh_n = bhh[128 + lane];
    float gir[2], giz[2], gin[2], ghr[2], ghz[2], ghn[2];
#pragma unroll
    for (int rr = 0; rr < 2; ++rr) {
      gir[rr] = bi_r; giz[rr] = bi_z; gin[rr] = bi_n;
      ghr[rr] = bh_r; ghz[rr] = bh_z; ghn[rr] = bh_n;
    }
#pragma unroll 4
    for (int kb = 0; kb < 16; ++kb) {
      int k0 = kb * 4;
      float4 wi[4], wh[4];
#pragma unroll
      for (int q = 0; q < 4; ++q) {
        wi[q] = wihP[(k0 + q) * 64 + lane];
        wh[q] = whhP[(k0 + q) * 64 + lane];
      }
#pragma unroll
      for (int rr = 0; rr < 2; ++rr) {
        const float4 s4 = *(const float4*)&sf_s[w * 2 + rr][k0];
        const float4 h4 = *(const float4*)&h_s[w * 2 + rr][k0];
        gir[rr] += s4.x * wi[0].x + s4.y * wi[1].x + s4.z * wi[2].x + s4.w * wi[3].x;
        giz[rr] += s4.x * wi[0].y + s4.y * wi[1].y + s4.z * wi[2].y + s4.w * wi[3].y;
        gin[rr] += s4.x * wi[0].z + s4.y * wi[1].z + s4.z * wi[2].z + s4.w * wi[3].z;
        ghr[rr] += h4.x * wh[0].x + h4.y * wh[1].x + h4.z * wh[2].x + h4.w * wh[3].x;
        ghz[rr] += h4.x * wh[0].y + h4.y * wh[1].y + h4.z * wh[2].y + h4.w * wh[3].y;
        ghn[rr] += h4.x * wh[0].z + h4.y * wh[1].z + h4.z * wh[2].z + h4.w * wh[3].z;
      }
    }
#pragma unroll
    for (int rr = 0; rr < 2; ++rr) {
      float rg = 1.f / (1.f + expf(-(gir[rr] + ghr[rr])));
      float zg = 1.f / (1.f + expf(-(giz[rr] + ghz[rr])));
      float ng = tanhf(gin[rr] + rg * ghn[rr]);
      hn_reg[rr] = (1.f - zg) * ng + zg * hp_reg[rr];
      hstate[((long)b * Nn + i0 + w * 2 + rr) * Hh + lane] = hn_reg[rr];
      hn_lds[w * 2 + rr][lane] = hn_reg[rr];
    }
  }
  __syncthreads();
  {
    int row = tid >> 5, m = tid & 31;
    float um = bm1[m];
    for (int k = 0; k < Hh; ++k) um += wm1T[k * M1 + m] * hn_lds[row][k];
    u_lds[row][m] = fmaxf(um, 0.f);
  }
  __syncthreads();
  if (tid < 8 * Fp) {
    int row = tid / Fp, f = tid - row * Fp;
    float pf = bm2[f];
#pragma unroll
    for (int m = 0; m < M1; ++m) pf += wm2T[m * Fp + f] * u_lds[row][m];
    int i = i0 + row;
    outp[(((long)b * PredL + p) * Nn + i) * Fp + f] = pf;
    xnext[((long)b * Nn + i) * Fp + f] = pf;
  }
}

// ---------------------------------------------------------------------------
extern "C" void kernel_launch(void* const* d_in, const int* in_sizes, int n_in,
                              void* d_out, int out_size, void* d_ws, size_t ws_size,
                              hipStream_t stream) {
  const float* hp     = (const float*)d_in[0];
  const float* hw     = (const float*)d_in[1];
  const float* adj    = (const float*)d_in[2];
  const float* coords = (const float*)d_in[3];
  const float* wgc1   = (const float*)d_in[4];
  const float* bgc1   = (const float*)d_in[5];
  const float* wgc2   = (const float*)d_in[6];
  const float* bgc2   = (const float*)d_in[7];
  const float* wih    = (const float*)d_in[8];
  const float* whh    = (const float*)d_in[9];
  const float* bih    = (const float*)d_in[10];
  const float* bhh    = (const float*)d_in[11];
  const float* wm1    = (const float*)d_in[12];
  const float* bm1    = (const float*)d_in[13];
  const float* wm2    = (const float*)d_in[14];
  const float* bm2    = (const float*)d_in[15];
  float* out = (float*)d_out;

  float* w = (float*)d_ws;
  float2* pk    = (float2*)w; w += Nn * Nn * 2;
  float* d23    = w; w += Bsz * Nn;
  float* e23    = w; w += Bsz * Nn;
  float* hstate = w; w += Bsz * Nn * Hh;
  float* sf_all = w; w += (long)Tt * Bsz * Nn * Hh;
  float* gi_ch  = w; w += (long)TCHUNK * Bsz * Nn * 3 * 64;
  float* h1d    = w; w += Bsz * Nn * Hh;
  float* xb0    = w; w += Bsz * Nn * Fp;
  float* xb1    = w; w += Bsz * Nn * Fp;
  float* A1d    = w; w += Bsz * Nn * Nn;
  float* A2d    = w; w += Bsz * Nn * Nn;
  float* wgc2T  = w; w += Hh * Hh;
  float* wm1T   = w; w += Hh * M1;
  float* wm2T   = w; w += M1 * Fp;
  float4* wihP  = (float4*)w; w += Hh * 64 * 4;
  float4* whhP  = (float4*)w; w += Hh * 64 * 4;

  k_prep<<<Nn + 1, 256, 0, stream>>>(coords, adj, wgc2, wih, whh, wm1, wm2,
                                     pk, wgc2T, wm1T, wm2T, wihP, whhP);
  k_enc<<<Tt * Bsz, 256, 0, stream>>>(pk, hp, hw, wgc1, bgc1, wgc2T, bgc2,
                                      sf_all, d23, e23);
  for (int s = 0; s < Tt / TCHUNK; ++s) {
    int t0 = s * TCHUNK;
    k_gi<<<(TCHUNK * Bsz * Nn) / 64, 256, 0, stream>>>(sf_all, wihP, bih,
                                                       gi_ch, t0);
    k_gru_scan4<<<Bsz * 16, 256, 0, stream>>>(gi_ch, whhP, bhh, hstate,
                                              t0, TCHUNK);
  }
  k_misc<<<Bsz * Nn + Bsz * Nn / 16, 256, 0, stream>>>(
      hw, pk, d23, e23, A1d, A2d, hstate, wm1T, bm1, wm2T, bm2, xb0);

  for (int p = 0; p < PredL; ++p) {
    float* xin  = (p & 1) ? xb1 : xb0;
    float* xout = (p & 1) ? xb0 : xb1;
    k_dstep_A<<<Bsz * 32, 256, 0, stream>>>(xin, A1d, wgc1, bgc1, h1d);
    k_dstep_B<<<Bsz * 32, 256, 0, stream>>>(
        A2d, h1d, wgc2T, bgc2, wihP, whhP, bih, bhh, hstate,
        wm1T, bm1, wm2T, bm2, out, xout, p);
  }
}